// Round 13
// baseline (630.506 us; speedup 1.0000x reference)
//
#include <hip/hip_runtime.h>

#define N_NODES 100000
#define N_EDGES 1600000
#define C 128
#define SCAN_B 1024
#define LDW 264            // padded LDS row stride (ushorts) for W staging

// bucket sort params
#define BSH 7              // bucket = dst >> 7 (128 nodes/bucket)
#define NBUCK 782          // ceil(100000 / 128)
#define BCAP 2560          // mean 2048, sigma 45 -> +11 sigma
#define TILE1 8192         // edges per phase-1 block
#define NBLK1 196          // ceil(1.6M / 8192)

#define NS 16              // nodes per agg wave-strip

typedef __attribute__((ext_vector_type(8))) short bfrag;   // 8 bf16 / 16 B
typedef __attribute__((ext_vector_type(4))) float f32x4;   // MFMA acc

// ---------- bf16 helpers ----------
__device__ __forceinline__ ushort f2b(float x) {
    uint u = __builtin_bit_cast(uint, x);
    u += 0x7fffu + ((u >> 16) & 1u);            // round-to-nearest-even
    return (ushort)(u >> 16);
}
__device__ __forceinline__ float b2f_lo(uint v) { return __builtin_bit_cast(float, v << 16); }
__device__ __forceinline__ float b2f_hi(uint v) { return __builtin_bit_cast(float, v & 0xFFFF0000u); }

// Slice-major feature layout: SM[s][n][u] (uint = bf16x2), s in [0,8), u in [0,8)
//   channel = s*16 + u*2 + {0,1};  uint index = (s*N + n)*8 + u
// Each 16-channel slice is contiguous 3.2 MB -> fits one XCD's 4 MB L2.

// ---------------- CSR build: 2-phase bucket sort ----------------

__global__ __launch_bounds__(256) void bucket_scatter2_k(
        const int* __restrict__ ei, uint* __restrict__ buck, int* __restrict__ bcur) {
    __shared__ int hist[NBUCK];
    __shared__ int base_l[NBUCK];
    int t = threadIdx.x;
    int tile0 = blockIdx.x * TILE1;

    for (int i = t; i < NBUCK; i += 256) hist[i] = 0;
    __syncthreads();
    #pragma unroll 4
    for (int j = 0; j < TILE1 / 256; ++j) {
        int e = tile0 + j * 256 + t;
        if (e < N_EDGES) atomicAdd(&hist[ei[N_EDGES + e] >> BSH], 1);
    }
    __syncthreads();
    for (int i = t; i < NBUCK; i += 256) {
        int h = hist[i];
        base_l[i] = h ? atomicAdd(&bcur[i], h) : 0;
    }
    __syncthreads();
    for (int i = t; i < NBUCK; i += 256) hist[i] = 0;
    __syncthreads();
    #pragma unroll 4
    for (int j = 0; j < TILE1 / 256; ++j) {
        int e = tile0 + j * 256 + t;
        if (e < N_EDGES) {
            int src = ei[e];
            int dst = ei[N_EDGES + e];
            int b = dst >> BSH;
            int r = base_l[b] + atomicAdd(&hist[b], 1);
            if (r < BCAP) buck[(uint)b * BCAP + r] = (uint)src | ((uint)(dst & 127) << 17);
        }
    }
}

__global__ __launch_bounds__(256) void bucket_hist2_k(
        const uint* __restrict__ buck, const int* __restrict__ bcur, int* __restrict__ deg) {
    __shared__ int cnt_l[128];
    int b = blockIdx.x, t = threadIdx.x;
    if (t < 128) cnt_l[t] = 0;
    __syncthreads();
    int cnt = min(bcur[b], BCAP);
    const uint* bp = buck + (uint)b * BCAP;
    for (int i = t; i < cnt; i += 256) atomicAdd(&cnt_l[bp[i] >> 17], 1);
    __syncthreads();
    int node = (b << BSH) + t;
    if (t < 128 && node < N_NODES) deg[node] = cnt_l[t];
}

__global__ void scan1_k(const int* __restrict__ deg, int* __restrict__ rowptr,
                        int* __restrict__ bsums) {
    __shared__ int s[256];
    int b = blockIdx.x, t = threadIdx.x;
    int base = b * SCAN_B + t * 4;
    int v[4];
    int sum = 0;
    #pragma unroll
    for (int j = 0; j < 4; ++j) {
        int idx = base + j;
        v[j] = (idx < N_NODES) ? deg[idx] : 0;
        sum += v[j];
    }
    s[t] = sum;
    __syncthreads();
    for (int off = 1; off < 256; off <<= 1) {
        int x = (t >= off) ? s[t - off] : 0;
        __syncthreads();
        s[t] += x;
        __syncthreads();
    }
    int run = (t > 0) ? s[t - 1] : 0;
    #pragma unroll
    for (int j = 0; j < 4; ++j) {
        run += v[j];
        int idx = base + j;
        if (idx < N_NODES) rowptr[idx + 1] = run;
    }
    if (t == 255) bsums[b] = s[255];
}

__global__ void scan2_k(int* __restrict__ bsums, int nb) {
    __shared__ int s[128];
    int t = threadIdx.x;
    s[t] = (t < nb) ? bsums[t] : 0;
    __syncthreads();
    for (int off = 1; off < 128; off <<= 1) {
        int x = (t >= off) ? s[t - off] : 0;
        __syncthreads();
        s[t] += x;
        __syncthreads();
    }
    if (t < nb) bsums[t] = (t > 0) ? s[t - 1] : 0;
}

__global__ void scan3_k(int* __restrict__ rowptr, const int* __restrict__ bsums) {
    int i = blockIdx.x * blockDim.x + threadIdx.x;
    if (i < N_NODES) rowptr[i + 1] += bsums[i / SCAN_B];
    if (i == 0) rowptr[0] = 0;
}

__global__ __launch_bounds__(256) void bucket_place2_k(
        const uint* __restrict__ buck, const int* __restrict__ bcur,
        const int* __restrict__ rowptr, int* __restrict__ col) {
    __shared__ int base_n[129];
    __shared__ int fill_l[128];
    __shared__ int col_l[BCAP];
    int b = blockIdx.x, t = threadIdx.x;
    int node0 = b << BSH;
    if (t <= 128) base_n[t] = rowptr[min(node0 + t, N_NODES)];
    if (t < 128) fill_l[t] = 0;
    __syncthreads();
    int pbase = base_n[0];
    int cnt = min(bcur[b], BCAP);
    const uint* bp = buck + (uint)b * BCAP;
    for (int i = t; i < cnt; i += 256) {
        uint p = bp[i];
        int rel = p >> 17;
        int pos = base_n[rel] + atomicAdd(&fill_l[rel], 1) - pbase;
        if (pos < BCAP) col_l[pos] = (int)(p & 0x1FFFFu);
    }
    __syncthreads();
    int total = min(base_n[128] - pbase, BCAP);
    for (int i = t; i < total; i += 256) col[pbase + i] = col_l[i];
}

// ---------------- prep: fp32 -> bf16 slice-major cast ----------------

__global__ void cast_x_sm_k(const float* __restrict__ in, uint* __restrict__ out) {
    int i = blockIdx.x * blockDim.x + threadIdx.x;   // N*64 uints
    if (i < N_NODES * 64) {
        int s = i / (N_NODES * 8);
        int rem = i - s * (N_NODES * 8);
        int n = rem >> 3, u = rem & 7;
        const float* p = in + (size_t)n * C + s * 16 + u * 2;
        out[i] = (uint)f2b(p[0]) | ((uint)f2b(p[1]) << 16);
    }
}

// both layers' wcat in one launch: wcat[o][k] = (k<128 ? Wl : Wr)[o][k&127]
__global__ void wprep2_k(const float* __restrict__ W1l, const float* __restrict__ W1r,
                         const float* __restrict__ W2l, const float* __restrict__ W2r,
                         ushort* __restrict__ wcat1, ushort* __restrict__ wcat2) {
    int i = blockIdx.x * blockDim.x + threadIdx.x;   // 65536
    int lay = i >> 15, p = i & 32767;
    int o = p >> 8, k = p & 255;
    const float* Wl = lay ? W2l : W1l;
    const float* Wr = lay ? W2r : W1r;
    ushort* wc = lay ? wcat2 : wcat1;
    float v = (k < 128) ? Wl[o * 128 + k] : Wr[o * 128 + (k - 128)];
    wc[p] = f2b(v);
}

// ---------------- mean aggregation: slice-major, XCD-pinned, strip waves ----------------
// Wave = 16-node strip x one 16-ch slice. slice = blockIdx&7 -> round-robin
// dispatch pins slice s to XCD s (R10 measured FETCH 177->41 MB with this).
// Per node: scalar rowptr, 1 vector NT col preload per 64 edges; per 8-edge
// chunk: 1 bpermute distributes 8 DIFFERENT edges (grp = lane>>3 picks edge,
// u = lane&7 picks channel-uint), 1 wave-load = 256 B = 8 slice rows; per-lane
// register accumulate; ONE 3-level shfl_xor reduce per node; 8-lane NT store.
__global__ __launch_bounds__(256) void agg_sl_k(
        const uint* __restrict__ feat,      // slice-major [8][N][8]
        uint* __restrict__ outb,            // slice-major
        const int* __restrict__ rowptr, const int* __restrict__ col) {
    int wave = threadIdx.x >> 6, lane = threadIdx.x & 63;
    int s = blockIdx.x & 7;
    int n0 = ((blockIdx.x >> 3) * 4 + wave) * NS;
    const uint* fs = feat + ((size_t)s * N_NODES << 3);
    int grp = lane >> 3, u = lane & 7;

    for (int i = 0; i < NS; ++i) {
        int node = n0 + i;
        if (node >= N_NODES) break;
        int beg = __builtin_amdgcn_readfirstlane(rowptr[node]);
        int end = __builtin_amdgcn_readfirstlane(rowptr[node + 1]);
        int deg = end - beg;
        float a0 = 0.f, a1 = 0.f;
        for (int e0 = beg; e0 < end; e0 += 64) {
            int cv = __builtin_nontemporal_load(&col[min(e0 + lane, end - 1)]);
            int nit = min(64, end - e0);
            for (int it = 0; it < nit; it += 8) {
                int j = it + grp;
                uint src = (uint)__shfl(cv, j);
                uint f = fs[((uint)src << 3) + u];
                bool ok = j < nit;
                a0 += ok ? b2f_lo(f) : 0.f;
                a1 += ok ? b2f_hi(f) : 0.f;
            }
        }
        a0 += __shfl_xor(a0, 8);  a1 += __shfl_xor(a1, 8);
        a0 += __shfl_xor(a0, 16); a1 += __shfl_xor(a1, 16);
        a0 += __shfl_xor(a0, 32); a1 += __shfl_xor(a1, 32);
        if (lane < 8) {
            float inv = 1.f / (float)max(deg, 1);
            uint o = (uint)f2b(a0 * inv) | ((uint)f2b(a1 * inv) << 16);
            __builtin_nontemporal_store(o, &outb[(((uint)s * N_NODES + (uint)node) << 3) + u]);
        }
    }
}

// ---------------- fused dual linear via MFMA, W staged in LDS ----------------
// A0/A1 slice-major. Frag channels k0 = c*32 + g*8: slice = 2c+(g>>1), uint off (g&1)*4.
// (validated in R9/R10)
template <bool RELU, bool OUT_BF16>
__global__ __launch_bounds__(256) void mfma_lin_k(
        const uint* __restrict__ A0,        // agg  slice-major
        const uint* __restrict__ A1,        // feat slice-major
        const ushort* __restrict__ W,       // wcat [128][256] bf16
        const float* __restrict__ bias,     // [128]
        void* __restrict__ outp) {
    __shared__ ushort wl[128 * LDW];        // 67.6 KB
    int t = threadIdx.x;

    const bfrag* wg = (const bfrag*)W;
    #pragma unroll
    for (int j = 0; j < 16; ++j) {
        int p = t + j * 256;
        int o = p >> 5, kb = p & 31;
        *(bfrag*)&wl[o * LDW + kb * 8] = wg[p];
    }
    __syncthreads();

    int wave = t >> 6, lane = t & 63;
    int g = lane >> 4, r16 = lane & 15;
    long base = (long)blockIdx.x * 128 + wave * 32;

    uint mr[2];
    #pragma unroll
    for (int mt = 0; mt < 2; ++mt) {
        long mrow = base + mt * 16 + r16;
        if (mrow >= N_NODES) mrow = N_NODES - 1;   // clamp loads; stores guarded
        mr[mt] = (uint)mrow;
    }
    uint su = (uint)(g >> 1);
    uint u0 = (uint)(g & 1) * 4;

    f32x4 acc[2][8];
    #pragma unroll
    for (int mt = 0; mt < 2; ++mt)
        #pragma unroll
        for (int nt = 0; nt < 8; ++nt) acc[mt][nt] = (f32x4){0.f, 0.f, 0.f, 0.f};

    #pragma unroll
    for (int c = 0; c < 8; ++c) {
        const uint* bp = (c < 4) ? A0 : A1;
        uint sidx = (uint)(c < 4 ? 2 * c : 2 * (c - 4)) + su;
        bfrag a[2];
        #pragma unroll
        for (int mt = 0; mt < 2; ++mt)
            a[mt] = *(const bfrag*)(bp + (((sidx * N_NODES + mr[mt]) << 3) + u0));
        #pragma unroll
        for (int nt = 0; nt < 8; ++nt) {
            bfrag b = *(const bfrag*)&wl[(nt * 16 + r16) * LDW + g * 8 + c * 32];
            acc[0][nt] = __builtin_amdgcn_mfma_f32_16x16x32_bf16(a[0], b, acc[0][nt], 0, 0, 0);
            acc[1][nt] = __builtin_amdgcn_mfma_f32_16x16x32_bf16(a[1], b, acc[1][nt], 0, 0, 0);
        }
    }

    #pragma unroll
    for (int nt = 0; nt < 8; ++nt) {
        int o = nt * 16 + r16;
        float bv = bias[o];
        #pragma unroll
        for (int mt = 0; mt < 2; ++mt) {
            #pragma unroll
            for (int i = 0; i < 4; ++i) {
                long orow = base + mt * 16 + g * 4 + i;
                if (orow < N_NODES) {
                    float v = acc[mt][nt][i] + bv;
                    if (RELU) v = fmaxf(v, 0.f);
                    if (OUT_BF16)   // slice-major bf16: slice=nt, ushort offset r16
                        ((ushort*)outp)[(((uint)nt * N_NODES + (uint)orow) << 4) + r16] = f2b(v);
                    else            // final output: row-major fp32
                        ((float*)outp)[orow * C + o] = v;
                }
            }
        }
    }
}

extern "C" void kernel_launch(void* const* d_in, const int* in_sizes, int n_in,
                              void* d_out, int out_size, void* d_ws, size_t ws_size,
                              hipStream_t stream) {
    const float* x   = (const float*)d_in[0];
    const int* ei    = (const int*)d_in[1];
    const float* W1l = (const float*)d_in[2];
    const float* b1  = (const float*)d_in[3];
    const float* W1r = (const float*)d_in[4];
    const float* W2l = (const float*)d_in[5];
    const float* b2  = (const float*)d_in[6];
    const float* W2r = (const float*)d_in[7];
    float* out       = (float*)d_out;

    char* ws = (char*)d_ws;
    size_t off = 0;
    uint* xb      = (uint*)(ws + off);   off += (size_t)N_NODES * C * 2;      // 25.6MB slice-major
    uint* aggb    = (uint*)(ws + off);   off += (size_t)N_NODES * C * 2;      // 25.6MB slice-major
    uint* hb      = (uint*)(ws + off);   off += (size_t)N_NODES * C * 2;      // 25.6MB slice-major
    uint* buck    = hb;   // 8.0MB bucket buffer aliases hb (hb written only after place2)
    ushort* wcat1 = (ushort*)(ws + off); off += (size_t)C * 256 * 2;          // 64KB
    ushort* wcat2 = (ushort*)(ws + off); off += (size_t)C * 256 * 2;          // 64KB
    int* col      = (int*)(ws + off);    off += (size_t)N_EDGES * 4;          // 6.4MB
    int* rowptr   = (int*)(ws + off);    off += (size_t)(N_NODES + 1) * 4;
    int* deg      = (int*)(ws + off);    off += (size_t)NBUCK * 128 * 4;      // 400KB
    int* bcur     = (int*)(ws + off);    off += 1024 * 4;
    int* bsums    = (int*)(ws + off);    off += 1024 * 4;

    int nb = (N_NODES + SCAN_B - 1) / SCAN_B;  // 98

    // --- CSR build: bucket sort with coalesced writeout ---
    hipMemsetAsync(bcur, 0, 1024 * 4, stream);
    bucket_scatter2_k<<<NBLK1, 256, 0, stream>>>(ei, buck, bcur);
    bucket_hist2_k<<<NBUCK, 256, 0, stream>>>(buck, bcur, deg);
    scan1_k<<<nb, 256, 0, stream>>>(deg, rowptr, bsums);
    scan2_k<<<1, 128, 0, stream>>>(bsums, nb);
    scan3_k<<<(N_NODES + 255) / 256, 256, 0, stream>>>(rowptr, bsums);
    bucket_place2_k<<<NBUCK, 256, 0, stream>>>(buck, bcur, rowptr, col);

    // --- prep bf16 (slice-major) ---
    cast_x_sm_k<<<(N_NODES * 64 + 255) / 256, 256, 0, stream>>>(x, xb);
    wprep2_k<<<256, 256, 0, stream>>>(W1l, W1r, W2l, W2r, wcat1, wcat2);

    int lin_blocks = (N_NODES + 127) / 128;                  // 782
    int agg_blocks = ((N_NODES + NS * 4 - 1) / (NS * 4)) * 8; // 1563*8 = 12504

    // --- layer 1 ---
    agg_sl_k<<<agg_blocks, 256, 0, stream>>>(xb, aggb, rowptr, col);
    mfma_lin_k<true, true><<<lin_blocks, 256, 0, stream>>>(aggb, xb, wcat1, b1, hb);

    // --- layer 2 ---
    agg_sl_k<<<agg_blocks, 256, 0, stream>>>(hb, aggb, rowptr, col);
    mfma_lin_k<false, false><<<lin_blocks, 256, 0, stream>>>(aggb, hb, wcat2, b2, out);
}

// Round 14
// 256.351 us; speedup vs baseline: 2.4595x; 2.4595x over previous
//
#include <hip/hip_runtime.h>

#define N_NODES 100000
#define N_EDGES 1600000
#define C 128
#define SCAN_B 1024
#define LDW 264            // padded LDS row stride (ushorts) for W staging

// bucket sort params
#define BSH 7              // bucket = dst >> 7 (128 nodes/bucket)
#define NBUCK 782          // ceil(100000 / 128)
#define BCAP 2560          // mean 2048, sigma 45 -> +11 sigma
#define TILE1 8192         // edges per phase-1 block
#define NBLK1 196          // ceil(1.6M / 8192)

typedef __attribute__((ext_vector_type(8))) short bfrag;   // 8 bf16 / 16 B
typedef __attribute__((ext_vector_type(4))) float f32x4;   // MFMA acc

// ---------- bf16 helpers ----------
__device__ __forceinline__ ushort f2b(float x) {
    uint u = __builtin_bit_cast(uint, x);
    u += 0x7fffu + ((u >> 16) & 1u);            // round-to-nearest-even
    return (ushort)(u >> 16);
}
__device__ __forceinline__ float b2f_lo(uint v) { return __builtin_bit_cast(float, v << 16); }
__device__ __forceinline__ float b2f_hi(uint v) { return __builtin_bit_cast(float, v & 0xFFFF0000u); }

// ---------------- CSR build: 2-phase bucket sort ----------------

__global__ __launch_bounds__(256) void bucket_scatter2_k(
        const int* __restrict__ ei, uint* __restrict__ buck, int* __restrict__ bcur) {
    __shared__ int hist[NBUCK];
    __shared__ int base_l[NBUCK];
    int t = threadIdx.x;
    int tile0 = blockIdx.x * TILE1;

    for (int i = t; i < NBUCK; i += 256) hist[i] = 0;
    __syncthreads();
    #pragma unroll 4
    for (int j = 0; j < TILE1 / 256; ++j) {
        int e = tile0 + j * 256 + t;
        if (e < N_EDGES) atomicAdd(&hist[ei[N_EDGES + e] >> BSH], 1);
    }
    __syncthreads();
    for (int i = t; i < NBUCK; i += 256) {
        int h = hist[i];
        base_l[i] = h ? atomicAdd(&bcur[i], h) : 0;
    }
    __syncthreads();
    for (int i = t; i < NBUCK; i += 256) hist[i] = 0;
    __syncthreads();
    #pragma unroll 4
    for (int j = 0; j < TILE1 / 256; ++j) {
        int e = tile0 + j * 256 + t;
        if (e < N_EDGES) {
            int src = ei[e];
            int dst = ei[N_EDGES + e];
            int b = dst >> BSH;
            int r = base_l[b] + atomicAdd(&hist[b], 1);
            if (r < BCAP) buck[(uint)b * BCAP + r] = (uint)src | ((uint)(dst & 127) << 17);
        }
    }
}

__global__ __launch_bounds__(256) void bucket_hist2_k(
        const uint* __restrict__ buck, const int* __restrict__ bcur, int* __restrict__ deg) {
    __shared__ int cnt_l[128];
    int b = blockIdx.x, t = threadIdx.x;
    if (t < 128) cnt_l[t] = 0;
    __syncthreads();
    int cnt = min(bcur[b], BCAP);
    const uint* bp = buck + (uint)b * BCAP;
    for (int i = t; i < cnt; i += 256) atomicAdd(&cnt_l[bp[i] >> 17], 1);
    __syncthreads();
    int node = (b << BSH) + t;
    if (t < 128 && node < N_NODES) deg[node] = cnt_l[t];
}

__global__ void scan1_k(const int* __restrict__ deg, int* __restrict__ rowptr,
                        int* __restrict__ bsums) {
    __shared__ int s[256];
    int b = blockIdx.x, t = threadIdx.x;
    int base = b * SCAN_B + t * 4;
    int v[4];
    int sum = 0;
    #pragma unroll
    for (int j = 0; j < 4; ++j) {
        int idx = base + j;
        v[j] = (idx < N_NODES) ? deg[idx] : 0;
        sum += v[j];
    }
    s[t] = sum;
    __syncthreads();
    for (int off = 1; off < 256; off <<= 1) {
        int x = (t >= off) ? s[t - off] : 0;
        __syncthreads();
        s[t] += x;
        __syncthreads();
    }
    int run = (t > 0) ? s[t - 1] : 0;
    #pragma unroll
    for (int j = 0; j < 4; ++j) {
        run += v[j];
        int idx = base + j;
        if (idx < N_NODES) rowptr[idx + 1] = run;
    }
    if (t == 255) bsums[b] = s[255];
}

__global__ void scan2_k(int* __restrict__ bsums, int nb) {
    __shared__ int s[128];
    int t = threadIdx.x;
    s[t] = (t < nb) ? bsums[t] : 0;
    __syncthreads();
    for (int off = 1; off < 128; off <<= 1) {
        int x = (t >= off) ? s[t - off] : 0;
        __syncthreads();
        s[t] += x;
        __syncthreads();
    }
    if (t < nb) bsums[t] = (t > 0) ? s[t - 1] : 0;
}

__global__ void scan3_k(int* __restrict__ rowptr, const int* __restrict__ bsums) {
    int i = blockIdx.x * blockDim.x + threadIdx.x;
    if (i < N_NODES) rowptr[i + 1] += bsums[i / SCAN_B];
    if (i == 0) rowptr[0] = 0;
}

// phase 2: rank bucket edges into LDS, fully-coalesced col writeout (plain src)
__global__ __launch_bounds__(256) void bucket_place2_k(
        const uint* __restrict__ buck, const int* __restrict__ bcur,
        const int* __restrict__ rowptr, int* __restrict__ col) {
    __shared__ int base_n[129];
    __shared__ int fill_l[128];
    __shared__ int col_l[BCAP];
    int b = blockIdx.x, t = threadIdx.x;
    int node0 = b << BSH;
    if (t <= 128) base_n[t] = rowptr[min(node0 + t, N_NODES)];
    if (t < 128) fill_l[t] = 0;
    __syncthreads();
    int pbase = base_n[0];
    int cnt = min(bcur[b], BCAP);
    const uint* bp = buck + (uint)b * BCAP;
    for (int i = t; i < cnt; i += 256) {
        uint p = bp[i];
        int rel = p >> 17;
        int pos = base_n[rel] + atomicAdd(&fill_l[rel], 1) - pbase;
        if (pos < BCAP) col_l[pos] = (int)(p & 0x1FFFFu);
    }
    __syncthreads();
    int total = min(base_n[128] - pbase, BCAP);
    for (int i = t; i < total; i += 256) col[pbase + i] = col_l[i];
}

// ---------------- prep: fp32 -> bf16 casts (row-major) ----------------

__global__ void cast_x_k(const float4* __restrict__ in, ushort4* __restrict__ out) {
    int i = blockIdx.x * blockDim.x + threadIdx.x;   // N*C/4 = 3.2M
    if (i < N_NODES * C / 4) {
        float4 v = in[i];
        ushort4 o = { f2b(v.x), f2b(v.y), f2b(v.z), f2b(v.w) };
        out[i] = o;
    }
}

// both layers' wcat in one launch: wcat[o][k] = (k<128 ? Wl : Wr)[o][k&127]
__global__ void wprep2_k(const float* __restrict__ W1l, const float* __restrict__ W1r,
                         const float* __restrict__ W2l, const float* __restrict__ W2r,
                         ushort* __restrict__ wcat1, ushort* __restrict__ wcat2) {
    int i = blockIdx.x * blockDim.x + threadIdx.x;   // 65536
    int lay = i >> 15, p = i & 32767;
    int o = p >> 8, k = p & 255;
    const float* Wl = lay ? W2l : W1l;
    const float* Wr = lay ? W2r : W1r;
    ushort* wc = lay ? wcat2 : wcat1;
    float v = (k < 128) ? Wl[o * 128 + k] : Wr[o * 128 + (k - 128)];
    wc[p] = f2b(v);
}

// ---------------- mean aggregation, bf16 features, scalar col path ----------------
// 1 wave per node; lane = channel pair. Edge indices WAVE-UNIFORM (readfirstlane
// beg/end) -> scalar col loads + saddr-form gathers. 16-deep main unroll
// (16 outstanding gathers), 8-deep mid, scalar tail. NT store (write-through
// anyway; avoids evicting feat lines from L2).
__global__ __launch_bounds__(256) void agg_bf16_k(
        const uint* __restrict__ feat,      // [N][64] uints (bf16x2)
        uint* __restrict__ outb,            // [N][64]
        const int* __restrict__ rowptr, const int* __restrict__ col) {
    int wave = threadIdx.x >> 6, lane = threadIdx.x & 63;
    int node = blockIdx.x * 4 + wave;
    int beg = __builtin_amdgcn_readfirstlane(rowptr[node]);
    int end = __builtin_amdgcn_readfirstlane(rowptr[node + 1]);
    int deg = end - beg;
    float a0 = 0.f, a1 = 0.f;
    int j = 0;
    for (; j + 16 <= deg; j += 16) {
        uint f[16];
        #pragma unroll
        for (int q = 0; q < 16; ++q) {
            uint s = (uint)col[beg + j + q];
            f[q] = feat[((size_t)s << 6) + lane];
        }
        #pragma unroll
        for (int q = 0; q < 16; ++q) { a0 += b2f_lo(f[q]); a1 += b2f_hi(f[q]); }
    }
    for (; j + 8 <= deg; j += 8) {
        uint f[8];
        #pragma unroll
        for (int q = 0; q < 8; ++q) {
            uint s = (uint)col[beg + j + q];
            f[q] = feat[((size_t)s << 6) + lane];
        }
        #pragma unroll
        for (int q = 0; q < 8; ++q) { a0 += b2f_lo(f[q]); a1 += b2f_hi(f[q]); }
    }
    for (; j < deg; ++j) {
        uint s = (uint)col[beg + j];
        uint f = feat[((size_t)s << 6) + lane];
        a0 += b2f_lo(f);
        a1 += b2f_hi(f);
    }
    float inv = 1.f / (float)max(deg, 1);
    uint o = (uint)f2b(a0 * inv) | ((uint)f2b(a1 * inv) << 16);
    __builtin_nontemporal_store(o, &outb[((uint)node << 6) + lane]);
}

// ---------------- fused dual linear via MFMA, W staged in LDS ----------------
template <bool RELU, bool OUT_BF16>
__global__ __launch_bounds__(256) void mfma_lin_k(
        const ushort* __restrict__ A0,      // agg  [M][128] bf16
        const ushort* __restrict__ A1,      // feat [M][128] bf16
        const ushort* __restrict__ W,       // wcat [128][256] bf16
        const float* __restrict__ bias,     // [128]
        void* __restrict__ outp) {
    __shared__ ushort wl[128 * LDW];        // 67.6 KB
    int t = threadIdx.x;

    const bfrag* wg = (const bfrag*)W;
    #pragma unroll
    for (int j = 0; j < 16; ++j) {
        int p = t + j * 256;
        int o = p >> 5, kb = p & 31;
        *(bfrag*)&wl[o * LDW + kb * 8] = wg[p];
    }
    __syncthreads();

    int wave = t >> 6, lane = t & 63;
    int g = lane >> 4, r16 = lane & 15;
    long base = (long)blockIdx.x * 128 + wave * 32;

    const ushort* a0p[2];
    const ushort* a1p[2];
    #pragma unroll
    for (int mt = 0; mt < 2; ++mt) {
        long mrow = base + mt * 16 + r16;
        if (mrow >= N_NODES) mrow = N_NODES - 1;   // clamp loads; stores guarded
        a0p[mt] = A0 + mrow * C + g * 8;
        a1p[mt] = A1 + mrow * C + g * 8;
    }

    f32x4 acc[2][8];
    #pragma unroll
    for (int mt = 0; mt < 2; ++mt)
        #pragma unroll
        for (int nt = 0; nt < 8; ++nt) acc[mt][nt] = (f32x4){0.f, 0.f, 0.f, 0.f};

    #pragma unroll
    for (int c = 0; c < 8; ++c) {
        bfrag a[2];
        #pragma unroll
        for (int mt = 0; mt < 2; ++mt)
            a[mt] = (c < 4) ? *(const bfrag*)(a0p[mt] + c * 32)
                            : *(const bfrag*)(a1p[mt] + (c - 4) * 32);
        #pragma unroll
        for (int nt = 0; nt < 8; ++nt) {
            bfrag b = *(const bfrag*)&wl[(nt * 16 + r16) * LDW + g * 8 + c * 32];
            acc[0][nt] = __builtin_amdgcn_mfma_f32_16x16x32_bf16(a[0], b, acc[0][nt], 0, 0, 0);
            acc[1][nt] = __builtin_amdgcn_mfma_f32_16x16x32_bf16(a[1], b, acc[1][nt], 0, 0, 0);
        }
    }

    #pragma unroll
    for (int nt = 0; nt < 8; ++nt) {
        int o = nt * 16 + r16;
        float bv = bias[o];
        #pragma unroll
        for (int mt = 0; mt < 2; ++mt) {
            #pragma unroll
            for (int i = 0; i < 4; ++i) {
                long orow = base + mt * 16 + g * 4 + i;
                if (orow < N_NODES) {
                    float v = acc[mt][nt][i] + bv;
                    if (RELU) v = fmaxf(v, 0.f);
                    if (OUT_BF16)
                        ((ushort*)outp)[orow * C + o] = f2b(v);
                    else
                        ((float*)outp)[orow * C + o] = v;
                }
            }
        }
    }
}

extern "C" void kernel_launch(void* const* d_in, const int* in_sizes, int n_in,
                              void* d_out, int out_size, void* d_ws, size_t ws_size,
                              hipStream_t stream) {
    const float* x   = (const float*)d_in[0];
    const int* ei    = (const int*)d_in[1];
    const float* W1l = (const float*)d_in[2];
    const float* b1  = (const float*)d_in[3];
    const float* W1r = (const float*)d_in[4];
    const float* W2l = (const float*)d_in[5];
    const float* b2  = (const float*)d_in[6];
    const float* W2r = (const float*)d_in[7];
    float* out       = (float*)d_out;

    char* ws = (char*)d_ws;
    size_t off = 0;
    ushort* xb    = (ushort*)(ws + off); off += (size_t)N_NODES * C * 2;      // 25.6MB
    ushort* aggb  = (ushort*)(ws + off); off += (size_t)N_NODES * C * 2;      // 25.6MB
    ushort* hb    = (ushort*)(ws + off); off += (size_t)N_NODES * C * 2;      // 25.6MB
    uint* buck    = (uint*)hb;   // 8.0MB bucket buffer aliases hb (hb written only after place2)
    ushort* wcat1 = (ushort*)(ws + off); off += (size_t)C * 256 * 2;          // 64KB
    ushort* wcat2 = (ushort*)(ws + off); off += (size_t)C * 256 * 2;          // 64KB
    int* col      = (int*)(ws + off);    off += (size_t)N_EDGES * 4;          // 6.4MB
    int* rowptr   = (int*)(ws + off);    off += (size_t)(N_NODES + 1) * 4;
    int* deg      = (int*)(ws + off);    off += (size_t)NBUCK * 128 * 4;      // 400KB
    int* bcur     = (int*)(ws + off);    off += 1024 * 4;
    int* bsums    = (int*)(ws + off);    off += 1024 * 4;

    int nb = (N_NODES + SCAN_B - 1) / SCAN_B;  // 98

    // --- CSR build: bucket sort with coalesced writeout ---
    hipMemsetAsync(bcur, 0, 1024 * 4, stream);
    bucket_scatter2_k<<<NBLK1, 256, 0, stream>>>(ei, buck, bcur);
    bucket_hist2_k<<<NBUCK, 256, 0, stream>>>(buck, bcur, deg);
    scan1_k<<<nb, 256, 0, stream>>>(deg, rowptr, bsums);
    scan2_k<<<1, 128, 0, stream>>>(bsums, nb);
    scan3_k<<<(N_NODES + 255) / 256, 256, 0, stream>>>(rowptr, bsums);
    bucket_place2_k<<<NBUCK, 256, 0, stream>>>(buck, bcur, rowptr, col);

    // --- prep bf16 ---
    cast_x_k<<<(N_NODES * C / 4 + 255) / 256, 256, 0, stream>>>((const float4*)x, (ushort4*)xb);
    wprep2_k<<<256, 256, 0, stream>>>(W1l, W1r, W2l, W2r, wcat1, wcat2);

    int lin_blocks = (N_NODES + 127) / 128;   // 782

    // --- layer 1 ---
    agg_bf16_k<<<N_NODES / 4, 256, 0, stream>>>((const uint*)xb, (uint*)aggb, rowptr, col);
    mfma_lin_k<true, true><<<lin_blocks, 256, 0, stream>>>(aggb, xb, wcat1, b1, hb);

    // --- layer 2 ---
    agg_bf16_k<<<N_NODES / 4, 256, 0, stream>>>((const uint*)hb, (uint*)aggb, rowptr, col);
    mfma_lin_k<false, false><<<lin_blocks, 256, 0, stream>>>(aggb, hb, wcat2, b2, out);
}